// Round 2
// baseline (472.834 us; speedup 1.0000x reference)
//
#include <hip/hip_runtime.h>
#include <stdint.h>

typedef __bf16 bf16x8 __attribute__((ext_vector_type(8)));
typedef float f32x16 __attribute__((ext_vector_type(16)));
typedef uint32_t u32x4 __attribute__((ext_vector_type(4)));

#define K_TOT 256
#define N_TOT 512
#define BM 128

__device__ __forceinline__ uint32_t pack_bf16x2(float a, float b) {
  // round-to-nearest-even f32 -> bf16, packed pair
  uint32_t ua = __builtin_bit_cast(uint32_t, a);
  uint32_t ub = __builtin_bit_cast(uint32_t, b);
  ua = (ua + 0x7FFFu + ((ua >> 16) & 1u)) >> 16;
  ub = (ub + 0x7FFFu + ((ub >> 16) & 1u)) >> 16;
  return ua | (ub << 16);
}

__global__ __launch_bounds__(512, 1)
void linear2d_kernel(const float* __restrict__ X, const float* __restrict__ W,
                     const float* __restrict__ Bias, float* __restrict__ O) {
  // As: [128 rows][128 k] bf16 (32 KB), Bs: [128 cols][128 k] bf16 (32 KB)
  // both XOR-swizzled: byte ^= (row&7)<<4  (T2; row stride 256B would be 16-way conflict)
  __shared__ alignas(16) uint8_t As[128 * 256];
  __shared__ alignas(16) uint8_t Bs[128 * 256];

  const int tid = threadIdx.x;
  const int lane = tid & 63;
  const int l31 = lane & 31;
  const int lhi = lane >> 5;          // 0/1 (k-group for 32x32x16 fragments)
  const int wid = tid >> 6;           // 0..7
  const int wr = wid >> 2;            // 0..1 -> 64-row group
  const int wc = wid & 3;             // 0..3 -> 32-col group within each N-chunk
  const long row0 = (long)blockIdx.x * BM;

  f32x16 acc[4][2];
  #pragma unroll
  for (int nc = 0; nc < 4; ++nc)
    #pragma unroll
    for (int m = 0; m < 2; ++m)
      #pragma unroll
      for (int i = 0; i < 16; ++i) acc[nc][m][i] = 0.0f;

  for (int kh = 0; kh < 2; ++kh) {
    // ---- stage A half-K: rows row0..row0+128, k in [kh*128, kh*128+128)
    {
      const float* src = X + row0 * K_TOT + kh * 128;
      #pragma unroll
      for (int i = 0; i < 8; ++i) {
        const int idx = tid + i * 512;
        const int r = idx >> 5;        // 0..127
        const int c4 = idx & 31;       // float4 index (32 per row-half)
        const float4 v = *(const float4*)(src + (long)r * K_TOT + c4 * 4);
        uint2 pk;
        pk.x = pack_bf16x2(v.x, v.y);
        pk.y = pack_bf16x2(v.z, v.w);
        *(uint2*)(As + r * 256 + ((c4 * 8) ^ ((r & 7) << 4))) = pk;
      }
    }
    __syncthreads();

    // ---- preload this wave's A fragments for the whole K-half (reused 4x)
    u32x4 afr[8][2];
    #pragma unroll
    for (int kk = 0; kk < 8; ++kk) {
      #pragma unroll
      for (int m = 0; m < 2; ++m) {
        const int r = wr * 64 + m * 32 + l31;
        afr[kk][m] = *(const u32x4*)(As + r * 256 +
                                     ((kk * 32 + lhi * 16) ^ ((r & 7) << 4)));
      }
    }

    #pragma unroll
    for (int nc = 0; nc < 4; ++nc) {
      // ---- stage B chunk: W rows [nc*128, +128), k in [kh*128, +128)
      {
        const float* src = W + (long)nc * 128 * K_TOT + kh * 128;
        #pragma unroll
        for (int i = 0; i < 8; ++i) {
          const int idx = tid + i * 512;
          const int r = idx >> 5;
          const int c4 = idx & 31;
          const float4 v = *(const float4*)(src + (long)r * K_TOT + c4 * 4);
          uint2 pk;
          pk.x = pack_bf16x2(v.x, v.y);
          pk.y = pack_bf16x2(v.z, v.w);
          *(uint2*)(Bs + r * 256 + ((c4 * 8) ^ ((r & 7) << 4))) = pk;
        }
      }
      __syncthreads();

      const int c = wc * 32 + l31;
      #pragma unroll
      for (int kk = 0; kk < 8; ++kk) {
        const bf16x8 bfr = __builtin_bit_cast(bf16x8,
            *(const u32x4*)(Bs + c * 256 +
                            ((kk * 32 + lhi * 16) ^ ((c & 7) << 4))));
        #pragma unroll
        for (int m = 0; m < 2; ++m) {
          acc[nc][m] = __builtin_amdgcn_mfma_f32_32x32x16_bf16(
              __builtin_bit_cast(bf16x8, afr[kk][m]), bfr, acc[nc][m], 0, 0, 0);
        }
      }
      __syncthreads();
    }
  }

  // ---- epilogue: bias + store (C/D layout: col=lane&31, row=(reg&3)+8*(reg>>2)+4*(lane>>5))
  #pragma unroll
  for (int nc = 0; nc < 4; ++nc) {
    const int col = nc * 128 + wc * 32 + l31;
    const float bias = Bias[col];
    #pragma unroll
    for (int m = 0; m < 2; ++m) {
      const long rbase = row0 + wr * 64 + m * 32 + lhi * 4;
      #pragma unroll
      for (int reg = 0; reg < 16; ++reg) {
        const long r = rbase + (reg & 3) + 8 * (reg >> 2);
        O[r * N_TOT + col] = acc[nc][m][reg] + bias;
      }
    }
  }
}

extern "C" void kernel_launch(void* const* d_in, const int* in_sizes, int n_in,
                              void* d_out, int out_size, void* d_ws, size_t ws_size,
                              hipStream_t stream) {
  const float* X = (const float*)d_in[0];
  const float* W = (const float*)d_in[1];
  const float* Bias = (const float*)d_in[2];
  float* O = (float*)d_out;
  const int M = in_sizes[0] / K_TOT;      // 131072
  const int grid = M / BM;                // 1024
  linear2d_kernel<<<dim3(grid), dim3(512), 0, stream>>>(X, W, Bias, O);
}